// Round 2
// baseline (263.470 us; speedup 1.0000x reference)
//
#include <hip/hip_runtime.h>
#include <cstddef>

// Sizes (fixed per reference): B=8192, D=784, H=256, E=32, K=512
#define NB 8192
#define ND 784
#define NH 256
#define NE 32
#define NK 512
#define ALPHA_F 1000.0f

// ---------------------------------------------------------------------------
// fp32 GEMM: C[M,N] = op(A[M,K] @ W[K,N] + bias), op = relu or id.
// BM=64, BN=64, BK=16, 256 threads, 4x4 outputs/thread, register prefetch.
// Grid: (M/64) x ceil(N/64).  Requires M%64==0, K%16==0, N%4==0.
// 2+ blocks/CU so barriers overlap across blocks; LDS reads are
// broadcast-heavy (A: 4 distinct addrs/wave, B: 2-way alias = free).
// ---------------------------------------------------------------------------
template<bool RELU>
__global__ __launch_bounds__(256)
void gemm_kernel(const float* __restrict__ A, const float* __restrict__ W,
                 const float* __restrict__ bias, float* __restrict__ C,
                 int M, int N, int K) {
    __shared__ float As[16][64];   // [k][m]
    __shared__ float Bs[16][64];   // [k][n]

    const int tid = threadIdx.x;
    const int bm  = blockIdx.x * 64;
    const int bn  = blockIdx.y * 64;
    const int tx  = tid & 15;      // 16 col-groups of 4
    const int ty  = tid >> 4;      // 16 row-groups of 4

    // A staging: thread -> row (tid>>2), k-offset (tid&3)*4  (one float4)
    const int arow = tid >> 2;
    const int ak   = (tid & 3) * 4;
    // B staging: thread -> k-row (tid>>4), col (tid&15)*4    (one float4)
    const int brow = tid >> 4;
    const int bcol = (tid & 15) * 4;

    const float* aptr = A + (size_t)(bm + arow) * K + ak;
    const int gcol = bn + bcol;
    const bool bvalid = (gcol < N);
    const float* wptr = W + (size_t)brow * N + (bvalid ? gcol : 0);

    float4 a0 = *(const float4*)(aptr);
    float4 bv = bvalid ? *(const float4*)(wptr) : make_float4(0.f, 0.f, 0.f, 0.f);

    float acc[4][4];
    #pragma unroll
    for (int i = 0; i < 4; ++i)
        #pragma unroll
        for (int j = 0; j < 4; ++j) acc[i][j] = 0.f;

    for (int k0 = 0; k0 < K; k0 += 16) {
        As[ak + 0][arow] = a0.x;
        As[ak + 1][arow] = a0.y;
        As[ak + 2][arow] = a0.z;
        As[ak + 3][arow] = a0.w;
        *(float4*)&Bs[brow][bcol] = bv;
        __syncthreads();

        const int k1 = k0 + 16;
        if (k1 < K) {
            a0 = *(const float4*)(aptr + k1);
            bv = bvalid ? *(const float4*)(wptr + (size_t)k1 * N)
                        : make_float4(0.f, 0.f, 0.f, 0.f);
        }

        #pragma unroll
        for (int kk = 0; kk < 16; ++kk) {
            float4 av = *(float4*)&As[kk][ty * 4];
            float4 bb = *(float4*)&Bs[kk][tx * 4];
            float a[4] = {av.x, av.y, av.z, av.w};
            float b[4] = {bb.x, bb.y, bb.z, bb.w};
            #pragma unroll
            for (int i = 0; i < 4; ++i)
                #pragma unroll
                for (int j = 0; j < 4; ++j)
                    acc[i][j] = fmaf(a[i], b[j], acc[i][j]);
        }
        __syncthreads();
    }

    const int gn = bn + tx * 4;
    if (gn < N) {
        float4 bb4 = *(const float4*)(bias + gn);
        #pragma unroll
        for (int i = 0; i < 4; ++i) {
            const int gm = bm + ty * 4 + i;
            float4 v;
            v.x = acc[i][0] + bb4.x;
            v.y = acc[i][1] + bb4.y;
            v.z = acc[i][2] + bb4.z;
            v.w = acc[i][3] + bb4.w;
            if (RELU) {
                v.x = fmaxf(v.x, 0.f); v.y = fmaxf(v.y, 0.f);
                v.z = fmaxf(v.z, 0.f); v.w = fmaxf(v.w, 0.f);
            }
            *(float4*)(C + (size_t)gm * N + gn) = v;
        }
    }
}

// ---------------------------------------------------------------------------
// Fused: emb[B,32] = h@W2+b2 ; h2[B,256] = relu(emb@W3+b3).
// Block = 16 rows, 256 threads, 512 blocks. emb round-trips through LDS.
// ---------------------------------------------------------------------------
__global__ __launch_bounds__(256)
void mid_kernel(const float* __restrict__ h, const float* __restrict__ W2,
                const float* __restrict__ b2, const float* __restrict__ W3,
                const float* __restrict__ b3, float* __restrict__ emb,
                float* __restrict__ h2) {
    __shared__ float es[16][32];
    const int tid = threadIdx.x;
    const int r0  = blockIdx.x * 16;

    // Phase 1: emb. Thread owns outputs o=tid and o=tid+256 (row=o>>5, col=o&31).
    #pragma unroll
    for (int half = 0; half < 2; ++half) {
        const int o   = tid + half * 256;
        const int row = o >> 5;
        const int col = o & 31;
        const float* hrow = h + (size_t)(r0 + row) * NH;
        float acc0 = 0.f, acc1 = 0.f;
        #pragma unroll 4
        for (int k = 0; k < NH; k += 4) {
            float4 hv = *(const float4*)(hrow + k);
            acc0 = fmaf(hv.x, W2[(k + 0) * NE + col], acc0);
            acc1 = fmaf(hv.y, W2[(k + 1) * NE + col], acc1);
            acc0 = fmaf(hv.z, W2[(k + 2) * NE + col], acc0);
            acc1 = fmaf(hv.w, W2[(k + 3) * NE + col], acc1);
        }
        float v = acc0 + acc1 + b2[col];
        es[row][col] = v;
        emb[(size_t)r0 * NE + o] = v;
    }
    __syncthreads();

    // Phase 2: h2. Thread owns column tid for all 16 rows.
    const int col = tid;
    float acc[16];
    #pragma unroll
    for (int r = 0; r < 16; ++r) acc[r] = 0.f;
    #pragma unroll
    for (int k = 0; k < NE; ++k) {
        float w = W3[k * NH + col];
        #pragma unroll
        for (int r = 0; r < 16; ++r) acc[r] = fmaf(es[r][k], w, acc[r]);
    }
    const float bb = b3[col];
    #pragma unroll
    for (int r = 0; r < 16; ++r) {
        float v = acc[r] + bb;
        h2[(size_t)(r0 + r) * NH + col] = v > 0.f ? v : 0.f;
    }
}

// ---------------------------------------------------------------------------
// Distances + stable softmin. Block = 8 rows, 256 threads.
// reps staged into LDS in 2 chunks of 256 clusters (pad stride 36 floats).
// Thread t owns clusters t and 256+t for all 8 rows.
// ---------------------------------------------------------------------------
__global__ __launch_bounds__(256)
void dist_kernel(const float* __restrict__ emb, const float* __restrict__ reps,
                 float* __restrict__ dist, float* __restrict__ wout) {
    __shared__ float reps_s[256 * 36];
    __shared__ float emb_s[8][32];
    __shared__ float smin[8][4];
    __shared__ float ssum[8][4];
    __shared__ float rowmin[8];
    __shared__ float rowsum[8];

    const int tid = threadIdx.x;
    const int r0  = blockIdx.x * 8;
    emb_s[tid >> 5][tid & 31] = emb[(size_t)r0 * NE + tid];

    float d[2][8];
    #pragma unroll
    for (int ch = 0; ch < 2; ++ch) {
        __syncthreads();  // emb_s ready (ch=0) / reps_s reuse safe (ch=1)
        for (int i = tid; i < 256 * 32; i += 256) {
            reps_s[(i >> 5) * 36 + (i & 31)] = reps[ch * 8192 + i];
        }
        __syncthreads();
        float4 rv[8];
        #pragma unroll
        for (int e4 = 0; e4 < 8; ++e4)
            rv[e4] = *(float4*)&reps_s[tid * 36 + e4 * 4];
        #pragma unroll
        for (int r = 0; r < 8; ++r) {
            float acc = 0.f;
            #pragma unroll
            for (int e4 = 0; e4 < 8; ++e4) {
                float4 ev = *(float4*)&emb_s[r][e4 * 4];
                float t0 = ev.x - rv[e4].x; acc = fmaf(t0, t0, acc);
                float t1 = ev.y - rv[e4].y; acc = fmaf(t1, t1, acc);
                float t2 = ev.z - rv[e4].z; acc = fmaf(t2, t2, acc);
                float t3 = ev.w - rv[e4].w; acc = fmaf(t3, t3, acc);
            }
            d[ch][r] = acc;
        }
    }

    const int lane = tid & 63;
    const int wid  = tid >> 6;

    #pragma unroll
    for (int r = 0; r < 8; ++r) {
        float m = fminf(d[0][r], d[1][r]);
        #pragma unroll
        for (int off = 32; off > 0; off >>= 1)
            m = fminf(m, __shfl_xor(m, off, 64));
        if (lane == 0) smin[r][wid] = m;
    }
    __syncthreads();
    if (tid < 8)
        rowmin[tid] = fminf(fminf(smin[tid][0], smin[tid][1]),
                            fminf(smin[tid][2], smin[tid][3]));
    __syncthreads();

    float e0[8], e1[8];
    #pragma unroll
    for (int r = 0; r < 8; ++r) {
        const float mm = rowmin[r];
        e0[r] = expf(-ALPHA_F * (d[0][r] - mm));
        e1[r] = expf(-ALPHA_F * (d[1][r] - mm));
        float s = e0[r] + e1[r];
        #pragma unroll
        for (int off = 32; off > 0; off >>= 1)
            s += __shfl_xor(s, off, 64);
        if (lane == 0) ssum[r][wid] = s;
    }
    __syncthreads();
    if (tid < 8)
        rowsum[tid] = (ssum[tid][0] + ssum[tid][1]) + (ssum[tid][2] + ssum[tid][3]);
    __syncthreads();

    #pragma unroll
    for (int r = 0; r < 8; ++r) {
        const size_t row = (size_t)(r0 + r);
        const float inv = 1.0f / rowsum[r];
        dist[row * NK + tid]       = d[0][r];
        dist[row * NK + 256 + tid] = d[1][r];
        wout[row * NK + tid]       = d[0][r] * (e0[r] * inv);
        wout[row * NK + 256 + tid] = d[1][r] * (e1[r] * inv);
    }
}

// ---------------------------------------------------------------------------
extern "C" void kernel_launch(void* const* d_in, const int* in_sizes, int n_in,
                              void* d_out, int out_size, void* d_ws, size_t ws_size,
                              hipStream_t stream) {
    const float* x    = (const float*)d_in[0];
    const float* reps = (const float*)d_in[1];
    const float* W1   = (const float*)d_in[2];
    const float* b1   = (const float*)d_in[3];
    const float* W2   = (const float*)d_in[4];
    const float* b2   = (const float*)d_in[5];
    const float* W3   = (const float*)d_in[6];
    const float* b3   = (const float*)d_in[7];
    const float* W4   = (const float*)d_in[8];
    const float* b4   = (const float*)d_in[9];

    float* out   = (float*)d_out;
    float* wout  = out;                              // [8192,512]
    float* dist  = out + (size_t)NB * NK;            // [8192,512]
    float* recon = out + (size_t)2 * NB * NK;        // [8192,784]
    float* emb   = out + (size_t)2 * NB * NK + (size_t)NB * ND;  // [8192,32]

    // h  (8192x256) aliases the distances region (overwritten only by dist_kernel)
    // h2 (8192x256) aliases the weighted region  (overwritten only by dist_kernel)
    float* h  = dist;
    float* h2 = wout;

    // 1) h = relu(x @ W1 + b1)     [8192,256], K=784 — grid 128x4 = 512 blocks
    gemm_kernel<true><<<dim3(128, 4), 256, 0, stream>>>(x, W1, b1, h, NB, NH, ND);
    // 2) emb + h2 fused            — 512 blocks
    mid_kernel<<<NB / 16, 256, 0, stream>>>(h, W2, b2, W3, b3, emb, h2);
    // 3) recon = h2 @ W4 + b4      [8192,784], K=256 — grid 128x13 = 1664 blocks
    gemm_kernel<false><<<dim3(128, 13), 256, 0, stream>>>(h2, W4, b4, recon, NB, ND, NH);
    // 4) distances + softmin       [8192,512]
    dist_kernel<<<NB / 8, 256, 0, stream>>>(emb, reps, dist, wout);
}

// Round 3
// 218.183 us; speedup vs baseline: 1.2076x; 1.2076x over previous
//
#include <hip/hip_runtime.h>
#include <cstddef>

// Sizes (fixed per reference): B=8192, D=784, H=256, E=32, K=512
#define NB 8192
#define ND 784
#define NH 256
#define NE 32
#define NK 512
#define ALPHA_F 1000.0f

typedef _Float16 h8 __attribute__((ext_vector_type(8)));
typedef _Float16 h4 __attribute__((ext_vector_type(4)));
typedef float f32x4 __attribute__((ext_vector_type(4)));

// ---------------------------------------------------------------------------
// Split fp32 -> (hi fp16, lo fp16 scaled by 2^11).  w ~= hi + lo * 2^-11,
// representation error ~2^-23|w|.  fp16*fp16 products are exact in the fp32
// MFMA accumulator, so a 3/4-term product expansion is fp32-class accurate.
// ---------------------------------------------------------------------------
__global__ __launch_bounds__(256)
void split_x_kernel(const float* __restrict__ x, _Float16* __restrict__ xhi,
                    _Float16* __restrict__ xlo, int n4) {
    int i = blockIdx.x * 256 + threadIdx.x;
    if (i >= n4) return;
    float4 v = ((const float4*)x)[i];
    float vv[4] = {v.x, v.y, v.z, v.w};
    h4 hi, lo;
    #pragma unroll
    for (int j = 0; j < 4; ++j) {
        _Float16 hh = (_Float16)vv[j];
        float r = vv[j] - (float)hh;
        hi[j] = hh;
        lo[j] = (_Float16)(r * 2048.0f);
    }
    ((h4*)xhi)[i] = hi;
    ((h4*)xlo)[i] = lo;
}

// W [K][N] fp32  ->  WT_hi/lo [N][K] fp16 (transposed, split). One block per n.
__global__ __launch_bounds__(256)
void splitw_kernel(const float* __restrict__ W, _Float16* __restrict__ hi,
                   _Float16* __restrict__ lo, int K, int N) {
    const int n = blockIdx.x;
    for (int k = threadIdx.x; k < K; k += 256) {
        float w = W[(size_t)k * N + n];
        _Float16 hh = (_Float16)w;
        float r = w - (float)hh;
        hi[(size_t)n * K + k] = hh;
        lo[(size_t)n * K + k] = (_Float16)(r * 2048.0f);
    }
}

// ---------------------------------------------------------------------------
// MFMA split-fp16 GEMM: C[M,N] = op(A[M,K] @ W[K,N] + bias)
// A given as hi/lo fp16 planes [M][K]; W given TRANSPOSED as hi/lo [N][K].
// Tile 64x64, BK=32, 256 threads = 4 waves, wave = 32x32 via 2x2 MFMA tiles
// of v_mfma_f32_16x16x32_f16.  TERMS=4: full hh+mid+ll (fp32-class, encoder);
// TERMS=3: drop ll (decoder).  K ragged: trailing 8-elem chunks zero-filled.
// LDS rows padded to 40 fp16 (80 B) to spread bank groups.
// ---------------------------------------------------------------------------
template<int TERMS, bool RELU>
__global__ __launch_bounds__(256)
void mfma_gemm(const _Float16* __restrict__ Ahi, const _Float16* __restrict__ Alo,
               const _Float16* __restrict__ WThi, const _Float16* __restrict__ WTlo,
               const float* __restrict__ bias, float* __restrict__ C,
               int N, int K, int KS) {
    __shared__ _Float16 smem[4 * 64 * 40];
    const int PA_HI = 0, PA_LO = 2560, PB_HI = 5120, PB_LO = 7680;

    const int tid = threadIdx.x;
    const int bm  = blockIdx.x * 64;
    const int bn  = blockIdx.y * 64;

    // staging: thread -> (row, 8-elem k-chunk)
    const int srow = tid >> 2;
    const int sq   = (tid & 3) * 8;
    const int arow_g = bm + srow;
    int brow_g = bn + srow; if (brow_g > N - 1) brow_g = N - 1;  // G4 edge tile

    const _Float16* pAhi = Ahi + (size_t)arow_g * K;
    const _Float16* pAlo = Alo + (size_t)arow_g * K;
    const _Float16* pBhi = WThi + (size_t)brow_g * K;
    const _Float16* pBlo = WTlo + (size_t)brow_g * K;

    auto ld8 = [&](const _Float16* p, int k) -> h8 {
        if (k + 8 <= K) return *(const h8*)(p + k);
        h8 z = {};
        return z;
    };

    h8 ra_hi = ld8(pAhi, sq), ra_lo = ld8(pAlo, sq);
    h8 rb_hi = ld8(pBhi, sq), rb_lo = ld8(pBlo, sq);

    // fragment coords
    const int lane = tid & 63;
    const int wv   = tid >> 6;
    const int mb   = (wv >> 1) * 32;
    const int nb   = (wv & 1) * 32;
    const int li   = lane & 15;
    const int kq   = (lane >> 4) * 8;

    f32x4 acc0[2][2] = {};
    f32x4 acc1[2][2] = {};
    f32x4 acc2[2][2] = {};

    const int soff = srow * 40 + sq;

    for (int s = 0; s < KS; ++s) {
        *(h8*)&smem[PA_HI + soff] = ra_hi;
        *(h8*)&smem[PA_LO + soff] = ra_lo;
        *(h8*)&smem[PB_HI + soff] = rb_hi;
        *(h8*)&smem[PB_LO + soff] = rb_lo;
        __syncthreads();

        if (s + 1 < KS) {
            const int kn = (s + 1) * 32 + sq;
            ra_hi = ld8(pAhi, kn); ra_lo = ld8(pAlo, kn);
            rb_hi = ld8(pBhi, kn); rb_lo = ld8(pBlo, kn);
        }

        h8 ahi[2], alo[2], bhi[2], blo[2];
        #pragma unroll
        for (int t = 0; t < 2; ++t) {
            const int ao = (mb + t * 16 + li) * 40 + kq;
            ahi[t] = *(const h8*)&smem[PA_HI + ao];
            alo[t] = *(const h8*)&smem[PA_LO + ao];
            const int bo = (nb + t * 16 + li) * 40 + kq;
            bhi[t] = *(const h8*)&smem[PB_HI + bo];
            blo[t] = *(const h8*)&smem[PB_LO + bo];
        }
        #pragma unroll
        for (int tm = 0; tm < 2; ++tm)
            #pragma unroll
            for (int tn = 0; tn < 2; ++tn) {
                acc0[tm][tn] = __builtin_amdgcn_mfma_f32_16x16x32_f16(
                    ahi[tm], bhi[tn], acc0[tm][tn], 0, 0, 0);
                acc1[tm][tn] = __builtin_amdgcn_mfma_f32_16x16x32_f16(
                    ahi[tm], blo[tn], acc1[tm][tn], 0, 0, 0);
                acc1[tm][tn] = __builtin_amdgcn_mfma_f32_16x16x32_f16(
                    alo[tm], bhi[tn], acc1[tm][tn], 0, 0, 0);
                if (TERMS == 4)
                    acc2[tm][tn] = __builtin_amdgcn_mfma_f32_16x16x32_f16(
                        alo[tm], blo[tn], acc2[tm][tn], 0, 0, 0);
            }
        __syncthreads();
    }

    const float c1 = 1.0f / 2048.0f;
    const float c2 = c1 * c1;
    const int quad = lane >> 4;
    #pragma unroll
    for (int tm = 0; tm < 2; ++tm)
        #pragma unroll
        for (int tn = 0; tn < 2; ++tn) {
            const int n = bn + nb + tn * 16 + li;
            if (n < N) {
                const float bv = bias[n];
                #pragma unroll
                for (int r = 0; r < 4; ++r) {
                    const int m = bm + mb + tm * 16 + quad * 4 + r;
                    float v = acc0[tm][tn][r] + c1 * acc1[tm][tn][r];
                    if (TERMS == 4) v += c2 * acc2[tm][tn][r];
                    v += bv;
                    if (RELU) v = fmaxf(v, 0.f);
                    C[(size_t)m * N + n] = v;
                }
            }
        }
}

// ---------------------------------------------------------------------------
// Fused: emb[B,32] = h@W2+b2 (fp32, precision-critical);
//        h2 = relu(emb@W3+b3) emitted as fp16 hi/lo planes for the MFMA GEMM.
// Block = 16 rows, 256 threads, 512 blocks.
// ---------------------------------------------------------------------------
__global__ __launch_bounds__(256)
void mid_kernel(const float* __restrict__ h, const float* __restrict__ W2,
                const float* __restrict__ b2, const float* __restrict__ W3,
                const float* __restrict__ b3, float* __restrict__ emb,
                _Float16* __restrict__ h2hi, _Float16* __restrict__ h2lo) {
    __shared__ float es[16][32];
    const int tid = threadIdx.x;
    const int r0  = blockIdx.x * 16;

    #pragma unroll
    for (int half = 0; half < 2; ++half) {
        const int o   = tid + half * 256;
        const int row = o >> 5;
        const int col = o & 31;
        const float* hrow = h + (size_t)(r0 + row) * NH;
        float acc0 = 0.f, acc1 = 0.f;
        #pragma unroll 4
        for (int k = 0; k < NH; k += 4) {
            float4 hv = *(const float4*)(hrow + k);
            acc0 = fmaf(hv.x, W2[(k + 0) * NE + col], acc0);
            acc1 = fmaf(hv.y, W2[(k + 1) * NE + col], acc1);
            acc0 = fmaf(hv.z, W2[(k + 2) * NE + col], acc0);
            acc1 = fmaf(hv.w, W2[(k + 3) * NE + col], acc1);
        }
        float v = acc0 + acc1 + b2[col];
        es[row][col] = v;
        emb[(size_t)r0 * NE + o] = v;
    }
    __syncthreads();

    const int col = tid;
    float acc[16];
    #pragma unroll
    for (int r = 0; r < 16; ++r) acc[r] = 0.f;
    #pragma unroll
    for (int k = 0; k < NE; ++k) {
        float w = W3[k * NH + col];
        #pragma unroll
        for (int r = 0; r < 16; ++r) acc[r] = fmaf(es[r][k], w, acc[r]);
    }
    const float bb = b3[col];
    #pragma unroll
    for (int r = 0; r < 16; ++r) {
        float v = acc[r] + bb;
        v = v > 0.f ? v : 0.f;
        _Float16 hh = (_Float16)v;
        float rr = v - (float)hh;
        h2hi[(size_t)(r0 + r) * NH + col] = hh;
        h2lo[(size_t)(r0 + r) * NH + col] = (_Float16)(rr * 2048.0f);
    }
}

// ---------------------------------------------------------------------------
// Distances + stable softmin (unchanged, verified). Block = 8 rows.
// ---------------------------------------------------------------------------
__global__ __launch_bounds__(256)
void dist_kernel(const float* __restrict__ emb, const float* __restrict__ reps,
                 float* __restrict__ dist, float* __restrict__ wout) {
    __shared__ float reps_s[256 * 36];
    __shared__ float emb_s[8][32];
    __shared__ float smin[8][4];
    __shared__ float ssum[8][4];
    __shared__ float rowmin[8];
    __shared__ float rowsum[8];

    const int tid = threadIdx.x;
    const int r0  = blockIdx.x * 8;
    emb_s[tid >> 5][tid & 31] = emb[(size_t)r0 * NE + tid];

    float d[2][8];
    #pragma unroll
    for (int ch = 0; ch < 2; ++ch) {
        __syncthreads();
        for (int i = tid; i < 256 * 32; i += 256) {
            reps_s[(i >> 5) * 36 + (i & 31)] = reps[ch * 8192 + i];
        }
        __syncthreads();
        float4 rv[8];
        #pragma unroll
        for (int e4 = 0; e4 < 8; ++e4)
            rv[e4] = *(float4*)&reps_s[tid * 36 + e4 * 4];
        #pragma unroll
        for (int r = 0; r < 8; ++r) {
            float acc = 0.f;
            #pragma unroll
            for (int e4 = 0; e4 < 8; ++e4) {
                float4 ev = *(float4*)&emb_s[r][e4 * 4];
                float t0 = ev.x - rv[e4].x; acc = fmaf(t0, t0, acc);
                float t1 = ev.y - rv[e4].y; acc = fmaf(t1, t1, acc);
                float t2 = ev.z - rv[e4].z; acc = fmaf(t2, t2, acc);
                float t3 = ev.w - rv[e4].w; acc = fmaf(t3, t3, acc);
            }
            d[ch][r] = acc;
        }
    }

    const int lane = tid & 63;
    const int wid  = tid >> 6;

    #pragma unroll
    for (int r = 0; r < 8; ++r) {
        float m = fminf(d[0][r], d[1][r]);
        #pragma unroll
        for (int off = 32; off > 0; off >>= 1)
            m = fminf(m, __shfl_xor(m, off, 64));
        if (lane == 0) smin[r][wid] = m;
    }
    __syncthreads();
    if (tid < 8)
        rowmin[tid] = fminf(fminf(smin[tid][0], smin[tid][1]),
                            fminf(smin[tid][2], smin[tid][3]));
    __syncthreads();

    float e0[8], e1[8];
    #pragma unroll
    for (int r = 0; r < 8; ++r) {
        const float mm = rowmin[r];
        e0[r] = expf(-ALPHA_F * (d[0][r] - mm));
        e1[r] = expf(-ALPHA_F * (d[1][r] - mm));
        float s = e0[r] + e1[r];
        #pragma unroll
        for (int off = 32; off > 0; off >>= 1)
            s += __shfl_xor(s, off, 64);
        if (lane == 0) ssum[r][wid] = s;
    }
    __syncthreads();
    if (tid < 8)
        rowsum[tid] = (ssum[tid][0] + ssum[tid][1]) + (ssum[tid][2] + ssum[tid][3]);
    __syncthreads();

    #pragma unroll
    for (int r = 0; r < 8; ++r) {
        const size_t row = (size_t)(r0 + r);
        const float inv = 1.0f / rowsum[r];
        dist[row * NK + tid]       = d[0][r];
        dist[row * NK + 256 + tid] = d[1][r];
        wout[row * NK + tid]       = d[0][r] * (e0[r] * inv);
        wout[row * NK + 256 + tid] = d[1][r] * (e1[r] * inv);
    }
}

// ---------------------------------------------------------------------------
extern "C" void kernel_launch(void* const* d_in, const int* in_sizes, int n_in,
                              void* d_out, int out_size, void* d_ws, size_t ws_size,
                              hipStream_t stream) {
    const float* x    = (const float*)d_in[0];
    const float* reps = (const float*)d_in[1];
    const float* W1   = (const float*)d_in[2];
    const float* b1   = (const float*)d_in[3];
    const float* W2   = (const float*)d_in[4];
    const float* b2   = (const float*)d_in[5];
    const float* W3   = (const float*)d_in[6];
    const float* b3   = (const float*)d_in[7];
    const float* W4   = (const float*)d_in[8];
    const float* b4   = (const float*)d_in[9];

    float* out   = (float*)d_out;
    float* wout  = out;                                          // [8192,512]
    float* dist  = out + (size_t)NB * NK;                        // [8192,512]
    float* recon = out + (size_t)2 * NB * NK;                    // [8192,784]
    float* emb   = out + (size_t)2 * NB * NK + (size_t)NB * ND;  // [8192,32]

    // Scratch aliased into output regions not yet written at time of use:
    //  recon region (24.5 MiB): x hi/lo fp16 planes (dead after GEMM1; recon
    //    is written by GEMM4 which reads only h2/W4T).
    //  dist region (16 MiB): h fp32 (8 MiB) + h2 hi/lo planes (4+4 MiB);
    //    all dead before dist_kernel overwrites.
    //  wout region: W1T/W4T hi/lo planes (1.6 MiB); dead before dist_kernel.
    _Float16* xhi   = (_Float16*)recon;
    _Float16* xlo   = xhi + (size_t)NB * ND;
    float*    h     = dist;
    _Float16* h2hi  = (_Float16*)(dist + (size_t)NB * NH);
    _Float16* h2lo  = h2hi + (size_t)NB * NH;
    _Float16* w1thi = (_Float16*)wout;
    _Float16* w1tlo = w1thi + (size_t)NH * ND;
    _Float16* w4thi = w1tlo + (size_t)NH * ND;
    _Float16* w4tlo = w4thi + (size_t)ND * NH;

    // 0) splits
    split_x_kernel<<<(NB * ND / 4 + 255) / 256, 256, 0, stream>>>(
        x, xhi, xlo, NB * ND / 4);
    splitw_kernel<<<NH, 256, 0, stream>>>(W1, w1thi, w1tlo, ND, NH);  // -> [256][784]
    splitw_kernel<<<ND, 256, 0, stream>>>(W4, w4thi, w4tlo, NH, ND);  // -> [784][256]

    // 1) h = relu(x @ W1 + b1)   M=8192 N=256 K=784, 25 K-steps (tail zero-filled)
    mfma_gemm<4, true><<<dim3(128, 4), 256, 0, stream>>>(
        xhi, xlo, w1thi, w1tlo, b1, h, NH, ND, 25);
    // 2) emb + h2 (fp16 planes)
    mid_kernel<<<NB / 16, 256, 0, stream>>>(h, W2, b2, W3, b3, emb, h2hi, h2lo);
    // 3) recon = h2 @ W4 + b4    M=8192 N=784 K=256, 8 K-steps
    mfma_gemm<3, false><<<dim3(128, 13), 256, 0, stream>>>(
        h2hi, h2lo, w4thi, w4tlo, b4, recon, ND, NH, 8);
    // 4) distances + softmin
    dist_kernel<<<NB / 8, 256, 0, stream>>>(emb, reps, dist, wout);
}